// Round 2
// baseline (1278.682 us; speedup 1.0000x reference)
//
#include <hip/hip_runtime.h>

// ---------------- types / helpers ----------------
typedef __bf16 bf16x8 __attribute__((ext_vector_type(8)));
typedef float  f32x4  __attribute__((ext_vector_type(4)));

__device__ __forceinline__ f32x4 MFMA(bf16x8 a, bf16x8 b, f32x4 c) {
    return __builtin_amdgcn_mfma_f32_16x16x32_bf16(a, b, c, 0, 0, 0);
}

__device__ __forceinline__ unsigned short f2bfu(float f) {
    unsigned int u = __builtin_bit_cast(unsigned int, f);
    u += 0x7FFFu + ((u >> 16) & 1u);
    return (unsigned short)(u >> 16);
}
__device__ __forceinline__ float bf2f(unsigned short s) {
    unsigned int u = ((unsigned int)s) << 16;
    return __builtin_bit_cast(float, u);
}
__device__ __forceinline__ float sigm(float x) { return 1.f / (1.f + __expf(-x)); }
__device__ __forceinline__ float tanh_f(float x) { return 1.f - 2.f / (__expf(2.f * x) + 1.f); }
// concrete dropout: z = sigmoid((plog + log u - log(1-u))/0.1); out = x*(1-z)/(1-p)
__device__ __forceinline__ float cdrop(float x, float u, float plog, float scale) {
    float t = (plog + __logf(u) - __logf(1.f - u)) * 10.f;
    float z = 1.f / (1.f + __expf(-t));
    return x * (1.f - z) * scale;
}

// ---------------- small kernels ----------------
__global__ void k_zero(float* acc) {
    if (threadIdx.x < 4) acc[threadIdx.x] = 0.f;
}

// Convert 5 weight matrices fp32 -> bf16 with K-padded layouts; accumulate sum(W*W)
__global__ void k_convert(const float* __restrict__ Win, const float* __restrict__ Wih,
                          const float* __restrict__ Whh, const float* __restrict__ Wfc1,
                          const float* __restrict__ Wfc2,
                          unsigned short* __restrict__ WinP, unsigned short* __restrict__ WihP,
                          unsigned short* __restrict__ WhhP, unsigned short* __restrict__ Wfc1P,
                          unsigned short* __restrict__ Wfc2b, float* __restrict__ acc) {
    __shared__ float s3[3];
    int tid = threadIdx.x;
    if (tid < 3) s3[tid] = 0.f;
    __syncthreads();
    int idx = blockIdx.x * 256 + tid;   // total 580608
    float sq = 0.f; int mi = -1;
    if (idx < 15360) {                                    // W_in [240][48] -> [240][64]
        int row = idx >> 6, kp = idx & 63;
        float v = (kp < 48) ? Win[row * 48 + kp] : 0.f;
        WinP[idx] = f2bfu(v);
        if (kp < 48) { sq = v * v; mi = 0; }
    } else if (idx < 15360 + 184320) {                    // W_ih [720][240] -> [720][256]
        int i = idx - 15360;
        int row = i >> 8, kp = i & 255;
        float v = (kp < 240) ? Wih[row * 240 + kp] : 0.f;
        WihP[i] = f2bfu(v);
    } else if (idx < 15360 + 368640) {                    // W_hh
        int i = idx - 15360 - 184320;
        int row = i >> 8, kp = i & 255;
        float v = (kp < 240) ? Whh[row * 240 + kp] : 0.f;
        WhhP[i] = f2bfu(v);
    } else if (idx < 15360 + 368640 + 131072) {           // W_fc1 [512][240] -> [512][256]
        int i = idx - 15360 - 368640;
        int row = i >> 8, kp = i & 255;
        float v = (kp < 240) ? Wfc1[row * 240 + kp] : 0.f;
        Wfc1P[i] = f2bfu(v);
        if (kp < 240) { sq = v * v; mi = 1; }
    } else if (idx < 15360 + 368640 + 131072 + 65536) {   // W_fc2 [128][512]
        int i = idx - 15360 - 368640 - 131072;
        float v = Wfc2[i];
        Wfc2b[i] = f2bfu(v);
        sq = v * v; mi = 2;
    }
    if (mi >= 0) atomicAdd(&s3[mi], sq);
    __syncthreads();
    if (tid < 3) atomicAdd(&acc[tid], s3[tid]);
}

// x_filt_prev_mean[b][m] = mean_s x_ens[s,b,m]
__global__ void k_colmean(const float* __restrict__ x_ens, float* __restrict__ xfpm) {
    int t = blockIdx.x * 256 + threadIdx.x;   // < 32768
    float s = 0.f;
    for (int ss = 0; ss < 32; ++ss) s += x_ens[ss * 32768 + t];
    xfpm[t] = s * (1.f / 32.f);
}

// per-b: x_pred_mean = xfpm @ F^T, innov = y_t - x_pred_mean @ H^T, feat[48]
__global__ void k_feat(const float* __restrict__ xfpm, const float* __restrict__ F_mat,
                       const float* __restrict__ H_mat, const float* __restrict__ y_t,
                       const float* __restrict__ y_prev, const float* __restrict__ xppm,
                       const float* __restrict__ xpdm, float* __restrict__ feat,
                       float* __restrict__ innov) {
    int b = blockIdx.x * 256 + threadIdx.x;
    if (b >= 2048) return;
    float xm[16];
    #pragma unroll
    for (int m = 0; m < 16; ++m) xm[m] = xfpm[b * 16 + m];
    float xpm[16];
    #pragma unroll
    for (int k = 0; k < 16; ++k) {
        float a = 0.f;
        #pragma unroll
        for (int m = 0; m < 16; ++m) a += xm[m] * F_mat[k * 16 + m];
        xpm[k] = a;
    }
    #pragma unroll
    for (int n = 0; n < 8; ++n) {
        float a = 0.f;
        #pragma unroll
        for (int k = 0; k < 16; ++k) a += xpm[k] * H_mat[n * 16 + k];
        float inn = y_t[b * 8 + n] - a;
        innov[b * 8 + n] = inn;
        feat[b * 48 + 16 + n] = inn;
        feat[b * 48 + 40 + n] = y_t[b * 8 + n] - y_prev[b * 8 + n];
    }
    #pragma unroll
    for (int m = 0; m < 16; ++m) {
        feat[b * 48 + m]      = xm[m] - xpdm[b * 16 + m];
        feat[b * 48 + 24 + m] = xm[m] - xppm[b * 16 + m];
    }
}

// ---------------- fused x1 + GRU kernel (32 rows/block) ----------------
__global__ __launch_bounds__(256, 4) void k_gru(
    const float* __restrict__ feat, const float* __restrict__ u_in_g,
    const float* __restrict__ h_ens, const float* __restrict__ u_fc1_g,
    const unsigned short* __restrict__ WinP, const unsigned short* __restrict__ WihP,
    const unsigned short* __restrict__ WhhP,
    const float* __restrict__ b_in, const float* __restrict__ b_ih,
    const float* __restrict__ b_hh,
    const float* __restrict__ p_in_l, const float* __restrict__ p_fc1_l,
    unsigned short* __restrict__ hdrop) {
    __shared__ __align__(16) unsigned short sAin[32 * 72];    // cdrop(feat,u_in) bf16, K-pad 64
    __shared__ __align__(16) unsigned short sA1[32 * 264];    // x1 bf16, K-pad 256
    __shared__ __align__(16) unsigned short sA2[32 * 264];    // h_ens bf16, K-pad 256
    int tid = threadIdx.x;
    int lane = tid & 63, wave = tid >> 6;
    int blk = blockIdx.x;
    int r0 = blk * 32;
    int b0 = (blk & 63) * 32;
    float plog_in = p_in_l[0];
    float sc_in = 1.f / (1.f - sigm(plog_in));
    float plog_f1 = p_fc1_l[0];
    float sc_f1 = 1.f / (1.f - sigm(plog_f1));

    // phase 0: stage A_in (with concrete dropout) and A2 (h_ens -> bf16)
    for (int c = tid; c < 384; c += 256) {
        int row = c / 12, k = (c % 12) * 4;
        float4 f = *(const float4*)(feat + (b0 + row) * 48 + k);
        float4 u = *(const float4*)(u_in_g + (size_t)(r0 + row) * 48 + k);
        ushort4 o;
        o.x = f2bfu(cdrop(f.x, u.x, plog_in, sc_in));
        o.y = f2bfu(cdrop(f.y, u.y, plog_in, sc_in));
        o.z = f2bfu(cdrop(f.z, u.z, plog_in, sc_in));
        o.w = f2bfu(cdrop(f.w, u.w, plog_in, sc_in));
        *(ushort4*)(sAin + row * 72 + k) = o;
    }
    if (tid < 128) {   // zero pad A_in k in [48,64)
        int row = tid / 4, k = 48 + (tid % 4) * 4;
        ushort4 z4 = {0, 0, 0, 0};
        *(ushort4*)(sAin + row * 72 + k) = z4;
    }
    for (int c = tid; c < 1920; c += 256) {
        int row = c / 60, k = (c % 60) * 4;
        float4 h = *(const float4*)(h_ens + (size_t)(r0 + row) * 240 + k);
        ushort4 o;
        o.x = f2bfu(h.x); o.y = f2bfu(h.y); o.z = f2bfu(h.z); o.w = f2bfu(h.w);
        *(ushort4*)(sA2 + row * 264 + k) = o;
    }
    if (tid < 192) {   // zero pads k in [240,264)
        int row = tid / 6, k = 240 + (tid % 6) * 4;
        ushort4 z4 = {0, 0, 0, 0};
        *(ushort4*)(sA2 + row * 264 + k) = z4;
        *(ushort4*)(sA1 + row * 264 + k) = z4;
    }
    __syncthreads();

    int ln = lane & 15, qd = lane >> 4;

    // phase 1: x1 = relu(A_in @ W_in^T + b_in) -> sA1
    for (int t = wave; t < 15; t += 4) {
        int col = t * 16 + ln;
        float bias = b_in[col];
        for (int sub = 0; sub < 2; ++sub) {
            f32x4 accv = {0.f, 0.f, 0.f, 0.f};
            #pragma unroll
            for (int kk = 0; kk < 2; ++kk) {
                bf16x8 a = *(const bf16x8*)(sAin + (sub * 16 + ln) * 72 + kk * 32 + qd * 8);
                bf16x8 b = *(const bf16x8*)(WinP + (size_t)(t * 16 + ln) * 64 + kk * 32 + qd * 8);
                accv = MFMA(a, b, accv);
            }
            #pragma unroll
            for (int i = 0; i < 4; ++i) {
                int row = sub * 16 + qd * 4 + i;
                float v = accv[i] + bias;
                v = v > 0.f ? v : 0.f;
                sA1[row * 264 + col] = f2bfu(v);
            }
        }
    }
    __syncthreads();

    // phase 2: GRU (6 MFMA chains per tile) + nonlinearity + cdrop
    for (int t = wave; t < 15; t += 4) {
        int j = t * 16 + ln;
        float bir_b = b_ih[j], biz_b = b_ih[240 + j], bin_b = b_ih[480 + j];
        float bhr_b = b_hh[j], bhz_b = b_hh[240 + j], bhn_b = b_hh[480 + j];
        for (int sub = 0; sub < 2; ++sub) {
            f32x4 air = {0,0,0,0}, aiz = {0,0,0,0}, ainn = {0,0,0,0};
            f32x4 ahr = {0,0,0,0}, ahz = {0,0,0,0}, ahn = {0,0,0,0};
            #pragma unroll
            for (int kk = 0; kk < 8; ++kk) {
                int ao = (sub * 16 + ln) * 264 + kk * 32 + qd * 8;
                bf16x8 a1 = *(const bf16x8*)(sA1 + ao);
                bf16x8 a2 = *(const bf16x8*)(sA2 + ao);
                int wo = kk * 32 + qd * 8;
                bf16x8 bir = *(const bf16x8*)(WihP + (size_t)j * 256 + wo);
                bf16x8 biz = *(const bf16x8*)(WihP + (size_t)(240 + j) * 256 + wo);
                bf16x8 bin_ = *(const bf16x8*)(WihP + (size_t)(480 + j) * 256 + wo);
                bf16x8 bhr = *(const bf16x8*)(WhhP + (size_t)j * 256 + wo);
                bf16x8 bhz = *(const bf16x8*)(WhhP + (size_t)(240 + j) * 256 + wo);
                bf16x8 bhn = *(const bf16x8*)(WhhP + (size_t)(480 + j) * 256 + wo);
                air = MFMA(a1, bir, air);
                aiz = MFMA(a1, biz, aiz);
                ainn = MFMA(a1, bin_, ainn);
                ahr = MFMA(a2, bhr, ahr);
                ahz = MFMA(a2, bhz, ahz);
                ahn = MFMA(a2, bhn, ahn);
            }
            #pragma unroll
            for (int i = 0; i < 4; ++i) {
                int row = sub * 16 + qd * 4 + i;
                float rg = sigm(air[i] + bir_b + ahr[i] + bhr_b);
                float zg = sigm(aiz[i] + biz_b + ahz[i] + bhz_b);
                float ng = tanh_f(ainn[i] + bin_b + rg * (ahn[i] + bhn_b));
                float hp = bf2f(sA2[row * 264 + j]);
                float hn2 = (1.f - zg) * ng + zg * hp;
                float u = u_fc1_g[(size_t)(r0 + row) * 240 + j];
                hdrop[(size_t)(r0 + row) * 240 + j] = f2bfu(cdrop(hn2, u, plog_f1, sc_f1));
            }
        }
    }
}

// ---------------- fused fc1 + fc2 + Kalman update kernel (32 rows/block) ----------------
__global__ __launch_bounds__(256, 3) void k_out(
    const unsigned short* __restrict__ hdrop, const float* __restrict__ u_fc2_g,
    const unsigned short* __restrict__ Wfc1P, const unsigned short* __restrict__ Wfc2b,
    const float* __restrict__ b_fc1, const float* __restrict__ b_fc2,
    const float* __restrict__ innov_ws, const float* __restrict__ x_ens,
    const float* __restrict__ F_mat, const float* __restrict__ p_fc2_l,
    float* __restrict__ out) {
    __shared__ __align__(16) unsigned short sA4[32 * 264];   // h_drop bf16, K-pad 256
    __shared__ __align__(16) unsigned short sA5[32 * 520];   // cdrop(x2) bf16, K=512
    __shared__ __align__(16) float sInn[256];
    __shared__ __align__(16) float sXe[512];
    __shared__ __align__(16) float sF[256];
    int tid = threadIdx.x;
    int lane = tid & 63, wave = tid >> 6;
    int blk = blockIdx.x;
    int r0 = blk * 32;
    int b0 = (blk & 63) * 32;
    float plog2 = p_fc2_l[0];
    float sc2 = 1.f / (1.f - sigm(plog2));

    // phase 0: stage
    for (int c = tid; c < 1920; c += 256) {
        int row = c / 60, k = (c % 60) * 4;
        *(ushort4*)(sA4 + row * 264 + k) =
            *(const ushort4*)(hdrop + (size_t)(r0 + row) * 240 + k);
    }
    if (tid < 192) {
        int row = tid / 6, k = 240 + (tid % 6) * 4;
        ushort4 z4 = {0, 0, 0, 0};
        *(ushort4*)(sA4 + row * 264 + k) = z4;
    }
    if (tid < 64) *(float4*)(sInn + tid * 4) = *(const float4*)(innov_ws + b0 * 8 + tid * 4);
    if (tid < 128) *(float4*)(sXe + tid * 4) = *(const float4*)(x_ens + (size_t)r0 * 16 + tid * 4);
    if (tid >= 128 && tid < 192) *(float4*)(sF + (tid - 128) * 4) = *(const float4*)(F_mat + (tid - 128) * 4);
    __syncthreads();

    int ln = lane & 15, qd = lane >> 4;

    // phase 1: x2 = relu(A4 @ W_fc1^T + b_fc1); cdrop(u_fc2) -> sA5
    for (int t = wave; t < 32; t += 4) {
        int col = t * 16 + ln;
        float bias = b_fc1[col];
        for (int sub = 0; sub < 2; ++sub) {
            f32x4 accv = {0.f, 0.f, 0.f, 0.f};
            #pragma unroll
            for (int kk = 0; kk < 8; ++kk) {
                bf16x8 a = *(const bf16x8*)(sA4 + (sub * 16 + ln) * 264 + kk * 32 + qd * 8);
                bf16x8 b = *(const bf16x8*)(Wfc1P + (size_t)col * 256 + kk * 32 + qd * 8);
                accv = MFMA(a, b, accv);
            }
            #pragma unroll
            for (int i = 0; i < 4; ++i) {
                int row = sub * 16 + qd * 4 + i;
                float v = accv[i] + bias;
                v = v > 0.f ? v : 0.f;
                float u = u_fc2_g[(size_t)(r0 + row) * 512 + col];
                sA5[row * 520 + col] = f2bfu(cdrop(v, u, plog2, sc2));
            }
        }
    }
    __syncthreads();

    // phase 2: K_vec = A5 @ W_fc2^T + b_fc2; x_filt = x_ens@F^T + K@innov
    for (int t = wave; t < 8; t += 4) {
        int j = t * 16 + ln;
        float bias = b_fc2[j];
        int n = lane & 7;
        int m = 2 * t + ((lane >> 3) & 1);
        for (int sub = 0; sub < 2; ++sub) {
            f32x4 accv = {0.f, 0.f, 0.f, 0.f};
            #pragma unroll
            for (int kk = 0; kk < 16; ++kk) {
                bf16x8 a = *(const bf16x8*)(sA5 + (sub * 16 + ln) * 520 + kk * 32 + qd * 8);
                bf16x8 b = *(const bf16x8*)(Wfc2b + (size_t)j * 512 + kk * 32 + qd * 8);
                accv = MFMA(a, b, accv);
            }
            #pragma unroll
            for (int i = 0; i < 4; ++i) {
                int row = sub * 16 + qd * 4 + i;
                float kv = accv[i] + bias;
                float pr = kv * sInn[row * 8 + n];
                pr += __shfl_xor(pr, 1);
                pr += __shfl_xor(pr, 2);
                pr += __shfl_xor(pr, 4);
                if (n == 0) {
                    float xpe = 0.f;
                    #pragma unroll
                    for (int jj = 0; jj < 16; ++jj) xpe += sXe[row * 16 + jj] * sF[m * 16 + jj];
                    out[(size_t)(r0 + row) * 16 + m] = xpe + pr;
                }
            }
        }
    }
}

// ---------------- regularizer ----------------
__global__ void k_reg(const float* __restrict__ acc, const float* __restrict__ pin,
                      const float* __restrict__ pfc1, const float* __restrict__ pfc2,
                      float* __restrict__ out) {
    float fan[3] = {48.f, 240.f, 512.f};
    float pl[3] = {pin[0], pfc1[0], pfc2[0]};
    float reg = 0.f;
    for (int i = 0; i < 3; ++i) {
        float p = 1.f / (1.f + expf(-pl[i]));
        reg += acc[i] / (1.f - p) + fan[i] * (p * logf(p) + (1.f - p) * logf(1.f - p));
    }
    if (threadIdx.x < 32) out[1048576 + threadIdx.x] = reg;
}

// ---------------- launch ----------------
extern "C" void kernel_launch(void* const* d_in, const int* in_sizes, int n_in,
                              void* d_out, int out_size, void* d_ws, size_t ws_size,
                              hipStream_t stream) {
    const float* y_t    = (const float*)d_in[0];
    const float* x_ens  = (const float*)d_in[1];
    const float* xppm   = (const float*)d_in[2];
    const float* xpdm   = (const float*)d_in[3];
    const float* y_prev = (const float*)d_in[4];
    const float* h_ens  = (const float*)d_in[5];
    const float* F_mat  = (const float*)d_in[6];
    const float* H_mat  = (const float*)d_in[7];
    const float* W_in   = (const float*)d_in[8];
    const float* b_in   = (const float*)d_in[9];
    const float* W_ih   = (const float*)d_in[10];
    const float* b_ih   = (const float*)d_in[11];
    const float* W_hh   = (const float*)d_in[12];
    const float* b_hh   = (const float*)d_in[13];
    const float* W_fc1  = (const float*)d_in[14];
    const float* b_fc1  = (const float*)d_in[15];
    const float* W_fc2  = (const float*)d_in[16];
    const float* b_fc2  = (const float*)d_in[17];
    const float* p_in   = (const float*)d_in[18];
    const float* p_fc1  = (const float*)d_in[19];
    const float* p_fc2  = (const float*)d_in[20];
    const float* u_in   = (const float*)d_in[21];
    const float* u_fc1  = (const float*)d_in[22];
    const float* u_fc2  = (const float*)d_in[23];

    char* ws = (char*)d_ws;
    float* acc            = (float*)(ws + 0);
    unsigned short* WinP  = (unsigned short*)(ws + 64);
    unsigned short* WihP  = (unsigned short*)(ws + 30784);
    unsigned short* WhhP  = (unsigned short*)(ws + 399424);
    unsigned short* Wfc1P = (unsigned short*)(ws + 768064);
    unsigned short* Wfc2b = (unsigned short*)(ws + 1030208);
    float* xfpm           = (float*)(ws + 1161280);
    float* feat           = (float*)(ws + 1292352);
    float* innov          = (float*)(ws + 1685568);
    unsigned short* hdrop = (unsigned short*)(ws + 1751104);   // end: 33,208,384 B
    float* out = (float*)d_out;

    k_zero<<<1, 64, 0, stream>>>(acc);
    k_convert<<<2268, 256, 0, stream>>>(W_in, W_ih, W_hh, W_fc1, W_fc2,
                                        WinP, WihP, WhhP, Wfc1P, Wfc2b, acc);
    k_colmean<<<128, 256, 0, stream>>>(x_ens, xfpm);
    k_feat<<<8, 256, 0, stream>>>(xfpm, F_mat, H_mat, y_t, y_prev, xppm, xpdm, feat, innov);
    k_gru<<<2048, 256, 0, stream>>>(feat, u_in, h_ens, u_fc1, WinP, WihP, WhhP,
                                    b_in, b_ih, b_hh, p_in, p_fc1, hdrop);
    k_out<<<2048, 256, 0, stream>>>(hdrop, u_fc2, Wfc1P, Wfc2b, b_fc1, b_fc2,
                                    innov, x_ens, F_mat, p_fc2, out);
    k_reg<<<1, 64, 0, stream>>>(acc, p_in, p_fc1, p_fc2, out);
}

// Round 3
// 845.564 us; speedup vs baseline: 1.5122x; 1.5122x over previous
//
#include <hip/hip_runtime.h>

// ---------------- types / helpers ----------------
typedef __bf16 bf16x8 __attribute__((ext_vector_type(8)));
typedef float  f32x4  __attribute__((ext_vector_type(4)));

__device__ __forceinline__ f32x4 MFMA(bf16x8 a, bf16x8 b, f32x4 c) {
    return __builtin_amdgcn_mfma_f32_16x16x32_bf16(a, b, c, 0, 0, 0);
}

__device__ __forceinline__ unsigned short f2bfu(float f) {
    unsigned int u = __builtin_bit_cast(unsigned int, f);
    u += 0x7FFFu + ((u >> 16) & 1u);
    return (unsigned short)(u >> 16);
}
__device__ __forceinline__ float bf2f(unsigned short s) {
    unsigned int u = ((unsigned int)s) << 16;
    return __builtin_bit_cast(float, u);
}
__device__ __forceinline__ float sigm(float x) { return 1.f / (1.f + __expf(-x)); }
__device__ __forceinline__ float tanh_f(float x) { return 1.f - 2.f / (__expf(2.f * x) + 1.f); }
// concrete dropout: z = sigmoid((plog + log u - log(1-u))/0.1); out = x*(1-z)/(1-p)
__device__ __forceinline__ float cdrop(float x, float u, float plog, float scale) {
    float t = (plog + __logf(u) - __logf(1.f - u)) * 10.f;
    float z = 1.f / (1.f + __expf(-t));
    return x * (1.f - z) * scale;
}

// ---------------- small kernels ----------------
__global__ void k_zero(float* acc) {
    if (threadIdx.x < 4) acc[threadIdx.x] = 0.f;
}

// Convert 5 weight matrices fp32 -> bf16 with K-padded layouts; accumulate sum(W*W)
__global__ void k_convert(const float* __restrict__ Win, const float* __restrict__ Wih,
                          const float* __restrict__ Whh, const float* __restrict__ Wfc1,
                          const float* __restrict__ Wfc2,
                          unsigned short* __restrict__ WinP, unsigned short* __restrict__ WihP,
                          unsigned short* __restrict__ WhhP, unsigned short* __restrict__ Wfc1P,
                          unsigned short* __restrict__ Wfc2b, float* __restrict__ acc) {
    __shared__ float s3[3];
    int tid = threadIdx.x;
    if (tid < 3) s3[tid] = 0.f;
    __syncthreads();
    int idx = blockIdx.x * 256 + tid;   // total 580608
    float sq = 0.f; int mi = -1;
    if (idx < 15360) {                                    // W_in [240][48] -> [240][64]
        int row = idx >> 6, kp = idx & 63;
        float v = (kp < 48) ? Win[row * 48 + kp] : 0.f;
        WinP[idx] = f2bfu(v);
        if (kp < 48) { sq = v * v; mi = 0; }
    } else if (idx < 15360 + 184320) {                    // W_ih [720][240] -> [720][256]
        int i = idx - 15360;
        int row = i >> 8, kp = i & 255;
        float v = (kp < 240) ? Wih[row * 240 + kp] : 0.f;
        WihP[i] = f2bfu(v);
    } else if (idx < 15360 + 368640) {                    // W_hh
        int i = idx - 15360 - 184320;
        int row = i >> 8, kp = i & 255;
        float v = (kp < 240) ? Whh[row * 240 + kp] : 0.f;
        WhhP[i] = f2bfu(v);
    } else if (idx < 15360 + 368640 + 131072) {           // W_fc1 [512][240] -> [512][256]
        int i = idx - 15360 - 368640;
        int row = i >> 8, kp = i & 255;
        float v = (kp < 240) ? Wfc1[row * 240 + kp] : 0.f;
        Wfc1P[i] = f2bfu(v);
        if (kp < 240) { sq = v * v; mi = 1; }
    } else if (idx < 15360 + 368640 + 131072 + 65536) {   // W_fc2 [128][512]
        int i = idx - 15360 - 368640 - 131072;
        float v = Wfc2[i];
        Wfc2b[i] = f2bfu(v);
        sq = v * v; mi = 2;
    }
    if (mi >= 0) atomicAdd(&s3[mi], sq);
    __syncthreads();
    if (tid < 3) atomicAdd(&acc[tid], s3[tid]);
}

// x_filt_prev_mean[b][m] = mean_s x_ens[s,b,m]
__global__ void k_colmean(const float* __restrict__ x_ens, float* __restrict__ xfpm) {
    int t = blockIdx.x * 256 + threadIdx.x;   // < 32768
    float s = 0.f;
    for (int ss = 0; ss < 32; ++ss) s += x_ens[ss * 32768 + t];
    xfpm[t] = s * (1.f / 32.f);
}

// per-b: x_pred_mean = xfpm @ F^T, innov = y_t - x_pred_mean @ H^T, feat[48]
__global__ void k_feat(const float* __restrict__ xfpm, const float* __restrict__ F_mat,
                       const float* __restrict__ H_mat, const float* __restrict__ y_t,
                       const float* __restrict__ y_prev, const float* __restrict__ xppm,
                       const float* __restrict__ xpdm, float* __restrict__ feat,
                       float* __restrict__ innov) {
    int b = blockIdx.x * 256 + threadIdx.x;
    if (b >= 2048) return;
    float xm[16];
    #pragma unroll
    for (int m = 0; m < 16; ++m) xm[m] = xfpm[b * 16 + m];
    float xpm[16];
    #pragma unroll
    for (int k = 0; k < 16; ++k) {
        float a = 0.f;
        #pragma unroll
        for (int m = 0; m < 16; ++m) a += xm[m] * F_mat[k * 16 + m];
        xpm[k] = a;
    }
    #pragma unroll
    for (int n = 0; n < 8; ++n) {
        float a = 0.f;
        #pragma unroll
        for (int k = 0; k < 16; ++k) a += xpm[k] * H_mat[n * 16 + k];
        float inn = y_t[b * 8 + n] - a;
        innov[b * 8 + n] = inn;
        feat[b * 48 + 16 + n] = inn;
        feat[b * 48 + 40 + n] = y_t[b * 8 + n] - y_prev[b * 8 + n];
    }
    #pragma unroll
    for (int m = 0; m < 16; ++m) {
        feat[b * 48 + m]      = xm[m] - xpdm[b * 16 + m];
        feat[b * 48 + 24 + m] = xm[m] - xppm[b * 16 + m];
    }
}

// x_pred_ens = x_ens @ F^T, written directly into the output buffer; k_out adds K@innov.
__global__ __launch_bounds__(256) void k_xpred(const float* __restrict__ x_ens,
                                               const float* __restrict__ F_mat,
                                               float* __restrict__ out) {
    __shared__ float sF[256];
    int tid = threadIdx.x;
    if (tid < 64) *(float4*)(sF + tid * 4) = *(const float4*)(F_mat + tid * 4);
    __syncthreads();
    size_t row = (size_t)blockIdx.x * 256 + tid;   // 65536 rows
    float x[16];
    #pragma unroll
    for (int q = 0; q < 4; ++q)
        *(float4*)(x + q * 4) = *(const float4*)(x_ens + row * 16 + q * 4);
    #pragma unroll
    for (int m = 0; m < 16; m += 4) {
        float4 o;
        float* op = (float*)&o;
        #pragma unroll
        for (int mm = 0; mm < 4; ++mm) {
            float a = 0.f;
            #pragma unroll
            for (int k2 = 0; k2 < 16; ++k2) a += sF[(m + mm) * 16 + k2] * x[k2];
            op[mm] = a;
        }
        *(float4*)(out + row * 16 + m) = o;
    }
}

// ---------------- fused x1 + GRU kernel (32 rows/block) ----------------
__global__ __launch_bounds__(256, 3) void k_gru(
    const float* __restrict__ feat, const float* __restrict__ u_in_g,
    const float* __restrict__ h_ens, const float* __restrict__ u_fc1_g,
    const unsigned short* __restrict__ WinP, const unsigned short* __restrict__ WihP,
    const unsigned short* __restrict__ WhhP,
    const float* __restrict__ b_in, const float* __restrict__ b_ih,
    const float* __restrict__ b_hh,
    const float* __restrict__ p_in_l, const float* __restrict__ p_fc1_l,
    unsigned short* __restrict__ hdrop) {
    __shared__ __align__(16) unsigned short sAin[32 * 72];    // cdrop(feat,u_in) bf16, K-pad 64
    __shared__ __align__(16) unsigned short sA1[32 * 264];    // x1 bf16, K-pad 256
    __shared__ __align__(16) unsigned short sA2[32 * 264];    // h_ens bf16, K-pad 256
    int tid = threadIdx.x;
    int lane = tid & 63, wave = tid >> 6;
    int blk = blockIdx.x;
    int r0 = blk * 32;
    int b0 = (blk & 63) * 32;
    float plog_in = p_in_l[0];
    float sc_in = 1.f / (1.f - sigm(plog_in));
    float plog_f1 = p_fc1_l[0];
    float sc_f1 = 1.f / (1.f - sigm(plog_f1));

    // phase 0: stage A_in (with concrete dropout) and A2 (h_ens -> bf16)
    for (int c = tid; c < 384; c += 256) {
        int row = c / 12, k = (c % 12) * 4;
        float4 f = *(const float4*)(feat + (b0 + row) * 48 + k);
        float4 u = *(const float4*)(u_in_g + (size_t)(r0 + row) * 48 + k);
        ushort4 o;
        o.x = f2bfu(cdrop(f.x, u.x, plog_in, sc_in));
        o.y = f2bfu(cdrop(f.y, u.y, plog_in, sc_in));
        o.z = f2bfu(cdrop(f.z, u.z, plog_in, sc_in));
        o.w = f2bfu(cdrop(f.w, u.w, plog_in, sc_in));
        *(ushort4*)(sAin + row * 72 + k) = o;
    }
    if (tid < 128) {   // zero pad A_in k in [48,64)
        int row = tid / 4, k = 48 + (tid % 4) * 4;
        ushort4 z4 = {0, 0, 0, 0};
        *(ushort4*)(sAin + row * 72 + k) = z4;
    }
    for (int c = tid; c < 1920; c += 256) {
        int row = c / 60, k = (c % 60) * 4;
        float4 h = *(const float4*)(h_ens + (size_t)(r0 + row) * 240 + k);
        ushort4 o;
        o.x = f2bfu(h.x); o.y = f2bfu(h.y); o.z = f2bfu(h.z); o.w = f2bfu(h.w);
        *(ushort4*)(sA2 + row * 264 + k) = o;
    }
    if (tid < 192) {   // zero pads k in [240,264)
        int row = tid / 6, k = 240 + (tid % 6) * 4;
        ushort4 z4 = {0, 0, 0, 0};
        *(ushort4*)(sA2 + row * 264 + k) = z4;
        *(ushort4*)(sA1 + row * 264 + k) = z4;
    }
    __syncthreads();

    int ln = lane & 15, qd = lane >> 4;

    // phase 1: x1 = relu(A_in @ W_in^T + b_in) -> sA1  (B hoisted over row sub-tiles)
    for (int t = wave; t < 15; t += 4) {
        int col = t * 16 + ln;
        float bias = b_in[col];
        f32x4 a0 = {0.f, 0.f, 0.f, 0.f}, a1v = {0.f, 0.f, 0.f, 0.f};
        #pragma unroll
        for (int kk = 0; kk < 2; ++kk) {
            bf16x8 b = *(const bf16x8*)(WinP + (size_t)col * 64 + kk * 32 + qd * 8);
            bf16x8 x0 = *(const bf16x8*)(sAin + ln * 72 + kk * 32 + qd * 8);
            bf16x8 x1 = *(const bf16x8*)(sAin + (16 + ln) * 72 + kk * 32 + qd * 8);
            a0 = MFMA(x0, b, a0);
            a1v = MFMA(x1, b, a1v);
        }
        #pragma unroll
        for (int i = 0; i < 4; ++i) {
            int row = qd * 4 + i;
            float v0 = a0[i] + bias;
            float v1 = a1v[i] + bias;
            sA1[row * 264 + col]        = f2bfu(v0 > 0.f ? v0 : 0.f);
            sA1[(16 + row) * 264 + col] = f2bfu(v1 > 0.f ? v1 : 0.f);
        }
    }
    __syncthreads();

    // phase 2: GRU — 6 MFMA chains x 2 row sub-tiles, B hoisted over sub-tiles
    for (int t = wave; t < 15; t += 4) {
        int j = t * 16 + ln;
        float bir_b = b_ih[j], biz_b = b_ih[240 + j], bin_b = b_ih[480 + j];
        float bhr_b = b_hh[j], bhz_b = b_hh[240 + j], bhn_b = b_hh[480 + j];
        f32x4 air0 = {0,0,0,0}, aiz0 = {0,0,0,0}, ain0 = {0,0,0,0};
        f32x4 ahr0 = {0,0,0,0}, ahz0 = {0,0,0,0}, ahn0 = {0,0,0,0};
        f32x4 air1 = {0,0,0,0}, aiz1 = {0,0,0,0}, ain1 = {0,0,0,0};
        f32x4 ahr1 = {0,0,0,0}, ahz1 = {0,0,0,0}, ahn1 = {0,0,0,0};
        #pragma unroll
        for (int kk = 0; kk < 8; ++kk) {
            int wo = kk * 32 + qd * 8;
            bf16x8 bir = *(const bf16x8*)(WihP + (size_t)j * 256 + wo);
            bf16x8 biz = *(const bf16x8*)(WihP + (size_t)(240 + j) * 256 + wo);
            bf16x8 bin_ = *(const bf16x8*)(WihP + (size_t)(480 + j) * 256 + wo);
            bf16x8 bhr = *(const bf16x8*)(WhhP + (size_t)j * 256 + wo);
            bf16x8 bhz = *(const bf16x8*)(WhhP + (size_t)(240 + j) * 256 + wo);
            bf16x8 bhn = *(const bf16x8*)(WhhP + (size_t)(480 + j) * 256 + wo);
            int ao0 = ln * 264 + wo;
            int ao1 = (16 + ln) * 264 + wo;
            bf16x8 a1_0 = *(const bf16x8*)(sA1 + ao0);
            bf16x8 a2_0 = *(const bf16x8*)(sA2 + ao0);
            bf16x8 a1_1 = *(const bf16x8*)(sA1 + ao1);
            bf16x8 a2_1 = *(const bf16x8*)(sA2 + ao1);
            air0 = MFMA(a1_0, bir, air0);  air1 = MFMA(a1_1, bir, air1);
            aiz0 = MFMA(a1_0, biz, aiz0);  aiz1 = MFMA(a1_1, biz, aiz1);
            ain0 = MFMA(a1_0, bin_, ain0); ain1 = MFMA(a1_1, bin_, ain1);
            ahr0 = MFMA(a2_0, bhr, ahr0);  ahr1 = MFMA(a2_1, bhr, ahr1);
            ahz0 = MFMA(a2_0, bhz, ahz0);  ahz1 = MFMA(a2_1, bhz, ahz1);
            ahn0 = MFMA(a2_0, bhn, ahn0);  ahn1 = MFMA(a2_1, bhn, ahn1);
        }
        auto epi = [&](int sub, f32x4 air, f32x4 aiz, f32x4 ainn, f32x4 ahr, f32x4 ahz, f32x4 ahn) {
            #pragma unroll
            for (int i = 0; i < 4; ++i) {
                int row = sub * 16 + qd * 4 + i;
                float rg = sigm(air[i] + bir_b + ahr[i] + bhr_b);
                float zg = sigm(aiz[i] + biz_b + ahz[i] + bhz_b);
                float ng = tanh_f(ainn[i] + bin_b + rg * (ahn[i] + bhn_b));
                float hp = bf2f(sA2[row * 264 + j]);
                float hn2 = (1.f - zg) * ng + zg * hp;
                float u = u_fc1_g[(size_t)(r0 + row) * 240 + j];
                hdrop[(size_t)(r0 + row) * 240 + j] = f2bfu(cdrop(hn2, u, plog_f1, sc_f1));
            }
        };
        epi(0, air0, aiz0, ain0, ahr0, ahz0, ahn0);
        epi(1, air1, aiz1, ain1, ahr1, ahz1, ahn1);
    }
}

// ---------------- fused fc1 + fc2 + Kalman update kernel (32 rows/block) ----------------
__global__ __launch_bounds__(256, 3) void k_out(
    const unsigned short* __restrict__ hdrop, const float* __restrict__ u_fc2_g,
    const unsigned short* __restrict__ Wfc1P, const unsigned short* __restrict__ Wfc2b,
    const float* __restrict__ b_fc1, const float* __restrict__ b_fc2,
    const float* __restrict__ innov_ws, const float* __restrict__ p_fc2_l,
    float* __restrict__ out) {
    __shared__ __align__(16) unsigned short sA4[32 * 264];   // h_drop bf16, K-pad 256
    __shared__ __align__(16) unsigned short sA5[32 * 520];   // cdrop(x2) bf16, K=512
    __shared__ __align__(16) float sInn[256];
    int tid = threadIdx.x;
    int lane = tid & 63, wave = tid >> 6;
    int blk = blockIdx.x;
    int r0 = blk * 32;
    int b0 = (blk & 63) * 32;
    float plog2 = p_fc2_l[0];
    float sc2 = 1.f / (1.f - sigm(plog2));

    // phase 0: stage
    for (int c = tid; c < 1920; c += 256) {
        int row = c / 60, k = (c % 60) * 4;
        *(ushort4*)(sA4 + row * 264 + k) =
            *(const ushort4*)(hdrop + (size_t)(r0 + row) * 240 + k);
    }
    if (tid < 192) {
        int row = tid / 6, k = 240 + (tid % 6) * 4;
        ushort4 z4 = {0, 0, 0, 0};
        *(ushort4*)(sA4 + row * 264 + k) = z4;
    }
    if (tid < 64) *(float4*)(sInn + tid * 4) = *(const float4*)(innov_ws + b0 * 8 + tid * 4);
    __syncthreads();

    int ln = lane & 15, qd = lane >> 4;

    // phase 1: x2 = relu(A4 @ W_fc1^T + b_fc1); cdrop(u_fc2) -> sA5 (B hoisted)
    for (int t = wave; t < 32; t += 4) {
        int col = t * 16 + ln;
        float bias = b_fc1[col];
        f32x4 a0 = {0.f, 0.f, 0.f, 0.f}, a1v = {0.f, 0.f, 0.f, 0.f};
        #pragma unroll
        for (int kk = 0; kk < 8; ++kk) {
            int wo = kk * 32 + qd * 8;
            bf16x8 b = *(const bf16x8*)(Wfc1P + (size_t)col * 256 + wo);
            bf16x8 x0 = *(const bf16x8*)(sA4 + ln * 264 + wo);
            bf16x8 x1 = *(const bf16x8*)(sA4 + (16 + ln) * 264 + wo);
            a0 = MFMA(x0, b, a0);
            a1v = MFMA(x1, b, a1v);
        }
        #pragma unroll
        for (int i = 0; i < 4; ++i) {
            int row = qd * 4 + i;
            float v0 = a0[i] + bias;
            float v1 = a1v[i] + bias;
            v0 = v0 > 0.f ? v0 : 0.f;
            v1 = v1 > 0.f ? v1 : 0.f;
            float u0 = u_fc2_g[(size_t)(r0 + row) * 512 + col];
            float u1 = u_fc2_g[(size_t)(r0 + 16 + row) * 512 + col];
            sA5[row * 520 + col]        = f2bfu(cdrop(v0, u0, plog2, sc2));
            sA5[(16 + row) * 520 + col] = f2bfu(cdrop(v1, u1, plog2, sc2));
        }
    }
    __syncthreads();

    // phase 2: K_vec = A5 @ W_fc2^T + b_fc2; out += K@innov (B hoisted)
    for (int t = wave; t < 8; t += 4) {
        int j = t * 16 + ln;
        float bias = b_fc2[j];
        int n = lane & 7;
        int m = 2 * t + ((lane >> 3) & 1);
        f32x4 a0 = {0.f, 0.f, 0.f, 0.f}, a1v = {0.f, 0.f, 0.f, 0.f};
        #pragma unroll
        for (int kk = 0; kk < 16; ++kk) {
            int wo = kk * 32 + qd * 8;
            bf16x8 b = *(const bf16x8*)(Wfc2b + (size_t)j * 512 + wo);
            bf16x8 x0 = *(const bf16x8*)(sA5 + ln * 520 + wo);
            bf16x8 x1 = *(const bf16x8*)(sA5 + (16 + ln) * 520 + wo);
            a0 = MFMA(x0, b, a0);
            a1v = MFMA(x1, b, a1v);
        }
        auto epi = [&](int sub, f32x4 accv) {
            #pragma unroll
            for (int i = 0; i < 4; ++i) {
                int row = sub * 16 + qd * 4 + i;
                float kv = accv[i] + bias;
                float pr = kv * sInn[row * 8 + n];
                pr += __shfl_xor(pr, 1);
                pr += __shfl_xor(pr, 2);
                pr += __shfl_xor(pr, 4);
                if (n == 0) {
                    size_t idx = (size_t)(r0 + row) * 16 + m;
                    out[idx] = out[idx] + pr;   // out pre-seeded with x_pred_ens by k_xpred
                }
            }
        };
        epi(0, a0);
        epi(1, a1v);
    }
}

// ---------------- regularizer ----------------
__global__ void k_reg(const float* __restrict__ acc, const float* __restrict__ pin,
                      const float* __restrict__ pfc1, const float* __restrict__ pfc2,
                      float* __restrict__ out) {
    float fan[3] = {48.f, 240.f, 512.f};
    float pl[3] = {pin[0], pfc1[0], pfc2[0]};
    float reg = 0.f;
    for (int i = 0; i < 3; ++i) {
        float p = 1.f / (1.f + expf(-pl[i]));
        reg += acc[i] / (1.f - p) + fan[i] * (p * logf(p) + (1.f - p) * logf(1.f - p));
    }
    if (threadIdx.x < 32) out[1048576 + threadIdx.x] = reg;
}

// ---------------- launch ----------------
extern "C" void kernel_launch(void* const* d_in, const int* in_sizes, int n_in,
                              void* d_out, int out_size, void* d_ws, size_t ws_size,
                              hipStream_t stream) {
    const float* y_t    = (const float*)d_in[0];
    const float* x_ens  = (const float*)d_in[1];
    const float* xppm   = (const float*)d_in[2];
    const float* xpdm   = (const float*)d_in[3];
    const float* y_prev = (const float*)d_in[4];
    const float* h_ens  = (const float*)d_in[5];
    const float* F_mat  = (const float*)d_in[6];
    const float* H_mat  = (const float*)d_in[7];
    const float* W_in   = (const float*)d_in[8];
    const float* b_in   = (const float*)d_in[9];
    const float* W_ih   = (const float*)d_in[10];
    const float* b_ih   = (const float*)d_in[11];
    const float* W_hh   = (const float*)d_in[12];
    const float* b_hh   = (const float*)d_in[13];
    const float* W_fc1  = (const float*)d_in[14];
    const float* b_fc1  = (const float*)d_in[15];
    const float* W_fc2  = (const float*)d_in[16];
    const float* b_fc2  = (const float*)d_in[17];
    const float* p_in   = (const float*)d_in[18];
    const float* p_fc1  = (const float*)d_in[19];
    const float* p_fc2  = (const float*)d_in[20];
    const float* u_in   = (const float*)d_in[21];
    const float* u_fc1  = (const float*)d_in[22];
    const float* u_fc2  = (const float*)d_in[23];

    char* ws = (char*)d_ws;
    float* acc            = (float*)(ws + 0);
    unsigned short* WinP  = (unsigned short*)(ws + 64);
    unsigned short* WihP  = (unsigned short*)(ws + 30784);
    unsigned short* WhhP  = (unsigned short*)(ws + 399424);
    unsigned short* Wfc1P = (unsigned short*)(ws + 768064);
    unsigned short* Wfc2b = (unsigned short*)(ws + 1030208);
    float* xfpm           = (float*)(ws + 1161280);
    float* feat           = (float*)(ws + 1292352);
    float* innov          = (float*)(ws + 1685568);
    unsigned short* hdrop = (unsigned short*)(ws + 1751104);   // end: 33,208,384 B
    float* out = (float*)d_out;

    k_zero<<<1, 64, 0, stream>>>(acc);
    k_convert<<<2268, 256, 0, stream>>>(W_in, W_ih, W_hh, W_fc1, W_fc2,
                                        WinP, WihP, WhhP, Wfc1P, Wfc2b, acc);
    k_colmean<<<128, 256, 0, stream>>>(x_ens, xfpm);
    k_feat<<<8, 256, 0, stream>>>(xfpm, F_mat, H_mat, y_t, y_prev, xppm, xpdm, feat, innov);
    k_xpred<<<256, 256, 0, stream>>>(x_ens, F_mat, out);
    k_gru<<<2048, 256, 0, stream>>>(feat, u_in, h_ens, u_fc1, WinP, WihP, WhhP,
                                    b_in, b_ih, b_hh, p_in, p_fc1, hdrop);
    k_out<<<2048, 256, 0, stream>>>(hdrop, u_fc2, Wfc1P, Wfc2b, b_fc1, b_fc2,
                                    innov, p_fc2, out);
    k_reg<<<1, 64, 0, stream>>>(acc, p_in, p_fc1, p_fc2, out);
}